// Round 11
// baseline (159.956 us; speedup 1.0000x reference)
//
#include <hip/hip_runtime.h>
#include <hip/hip_fp16.h>

// DSA varlen sparse attention, MI355X — round 11 (corrected).
// See theory above: first structure with per-wave VALU << TA. MFMA fp16
// scores (plain-layout A-frags, full-line gathers), exp/sc once per row in
// the bounce, PV reads packed (w,g) pairs from LDS.

#define T_TOK 4096
#define NH    16
#define HD    64
#define KSEL  64
#define KV_ELEMS (T_TOK * NH * HD)     // 4194304 per tensor

typedef _Float16 h8 __attribute__((ext_vector_type(8)));
typedef float    f4v __attribute__((ext_vector_type(4)));

static __device__ __forceinline__ __half2 u2h2(unsigned u) {
    return __builtin_bit_cast(__half2, u);
}
static __device__ __forceinline__ unsigned h22u(__half2 h) {
    return __builtin_bit_cast(unsigned, h);
}
template<int CTRL>
static __device__ __forceinline__ float dpp_addf(float x) {
    const int s = __builtin_amdgcn_update_dpp(
        0, __builtin_bit_cast(int, x), CTRL, 0xF, 0xF, true);
    return x + __builtin_bit_cast(float, s);
}
template<int IMM>
static __device__ __forceinline__ float swz_addf(float x) {
    const int s = __builtin_amdgcn_ds_swizzle(__builtin_bit_cast(int, x), IMM);
    return x + __builtin_bit_cast(float, s);
}
template<int IMM>
static __device__ __forceinline__ __half2 swz_hadd2(__half2 x) {
    const int s = __builtin_amdgcn_ds_swizzle(__builtin_bit_cast(int, x), IMM);
    return __hadd2(x, __builtin_bit_cast(__half2, s));
}
static __device__ __forceinline__ __half2 sh32_hadd2(__half2 x) {
    const int s = __shfl_xor(__builtin_bit_cast(int, x), 32, 64);
    return __hadd2(x, __builtin_bit_cast(__half2, s));
}

__global__ __launch_bounds__(256) void cvt_fp16(
    const float4* __restrict__ kM, const float4* __restrict__ vM,
    uint2* __restrict__ kH, uint2* __restrict__ vH)
{
    const int n4 = KV_ELEMS / 4;
    const int i  = blockIdx.x * blockDim.x + threadIdx.x;
    const bool isK = i < n4;
    const float4 f = isK ? kM[i] : vM[i - n4];
    uint2 u;
    u.x = h22u(__floats2half2_rn(f.x, f.y));
    u.y = h22u(__floats2half2_rn(f.z, f.w));
    if (isK) kH[i] = u; else vH[i - n4] = u;
}

__global__ __launch_bounds__(256) void dsa_sparse_attn(
    const float*  __restrict__ qM,
    const __half* __restrict__ kH,
    const __half* __restrict__ vH,
    const int*    __restrict__ cu,
    const int*    __restrict__ tidx,
    const float*  __restrict__ tsc,
    float*        __restrict__ out,
    int num_docs)
{
    __shared__ uint2 s_wg[4][64];   // 2 KB: per-row (packed half2 w, g)

    const int wave = threadIdx.x >> 6;
    const int lane = threadIdx.x & 63;

    const int b            = blockIdx.x;
    const int xcd          = b & 7;
    const int j            = b >> 3;
    const int token_block  = j & 255;
    const int slice_within = j >> 8;
    const int s            = xcd + (slice_within << 3);
    const int h            = s & (NH - 1);
    const int t            = (s >> 4) * (T_TOK / 4) + token_block * 4 + wave;
    const int gid          = t * NH + h;

    int seg = 0;
    for (int i = 1; i < num_docs; ++i)
        if (t >= cu[i]) seg = i;
    const int start = cu[seg];
    const int len   = cu[seg + 1] - start;

    int loc = tidx[t * KSEL + lane] - start;
    loc = loc < 0 ? 0 : (loc > len - 1 ? len - 1 : loc);
    const int g = start + loc;
    const float sc = tsc[t * KSEL + lane];

    const int quad = lane >> 4;

    // ===== QK^T on MFMA: A-frags from plain fp16 rows, full-line gathers =====
    const uint4* kf = (const uint4*)kH;        // fp16 row = 8 uint4 (128B)
    uint4 a1[4], a2[4];
    #pragma unroll
    for (int g4 = 0; g4 < 4; ++g4) {
        const int gr = __shfl(g, g4 * 16 + (lane & 15), 64);
        const int base = (gr * NH + h) * 8 + quad;
        a1[g4] = kf[base];        // dims [8q,+8)   (line 0 of row)
        a2[g4] = kf[base + 4];    // dims [32+8q,+8)(line 1 of row)
    }
    const float* qrow = qM + gid * HD;
    const float4 qa = *(const float4*)(qrow + quad * 8);
    const float4 qb = *(const float4*)(qrow + quad * 8 + 4);
    const float4 qc = *(const float4*)(qrow + 32 + quad * 8);
    const float4 qd = *(const float4*)(qrow + 32 + quad * 8 + 4);
    uint4 qu1, qu2;
    qu1.x = h22u(__floats2half2_rn(qa.x, qa.y));
    qu1.y = h22u(__floats2half2_rn(qa.z, qa.w));
    qu1.z = h22u(__floats2half2_rn(qb.x, qb.y));
    qu1.w = h22u(__floats2half2_rn(qb.z, qb.w));
    qu2.x = h22u(__floats2half2_rn(qc.x, qc.y));
    qu2.y = h22u(__floats2half2_rn(qc.z, qc.w));
    qu2.z = h22u(__floats2half2_rn(qd.x, qd.y));
    qu2.w = h22u(__floats2half2_rn(qd.z, qd.w));
    const h8 qb1 = __builtin_bit_cast(h8, qu1);
    const h8 qb2 = __builtin_bit_cast(h8, qu2);

    f4v D[4];
    #pragma unroll
    for (int g4 = 0; g4 < 4; ++g4) {
        f4v d = {0.f, 0.f, 0.f, 0.f};
        d = __builtin_amdgcn_mfma_f32_16x16x32_f16(
                __builtin_bit_cast(h8, a1[g4]), qb1, d, 0, 0, 0);
        d = __builtin_amdgcn_mfma_f32_16x16x32_f16(
                __builtin_bit_cast(h8, a2[g4]), qb2, d, 0, 0, 0);
        D[g4] = d;
    }

    // ===== Bounce: lane -> one row; write (w, g); wave-reduce S2 =====
    float S2;
    {
        const f4v Ta = ((lane >> 2) & 1) ? D[1] : D[0];
        const f4v Tb = ((lane >> 2) & 1) ? D[3] : D[2];
        const f4v Tg = ((lane >> 3) & 1) ? Tb : Ta;
        const float va  = (lane & 1) ? Tg.y : Tg.x;
        const float vb  = (lane & 1) ? Tg.w : Tg.z;
        const float sv  = (lane & 2) ? vb : va;
        const int roww = 16 * ((lane >> 2) & 3) + 4 * quad + (lane & 3);
        const float scr = __shfl(sc, roww, 64);
        const int   grw = __shfl(g,  roww, 64);
        const float w = __expf(sv * 0.125f) * scr;   // unnormalized (R7-proven)
        uint2 wg;
        wg.x = h22u(__floats2half2_rn(w, w));
        wg.y = (unsigned)grw;
        s_wg[wave][roww] = wg;
        float r = w;
        r = dpp_addf<0xB1>(r);
        r = dpp_addf<0x4E>(r);
        r = dpp_addf<0x141>(r);
        r = dpp_addf<0x140>(r);
        r = swz_addf<0x401F>(r);
        r += __shfl_xor(r, 32, 64);
        S2 = r;
    }

    // ===== PV: fp16 V, half2 accumulate; (w,g) from LDS =====
    const int laneQ8 = lane >> 3;
    const int laneC8 = lane & 7;
    const uint4* vf = (const uint4*)vH;

    __half2 acc0 = u2h2(0u), acc1 = u2h2(0u), acc2 = u2h2(0u), acc3 = u2h2(0u);
    #pragma unroll
    for (int rg = 0; rg < 8; ++rg) {
        const uint2 wg = s_wg[wave][rg * 8 + laneQ8];
        const __half2 w2 = u2h2(wg.x);
        const int gv = (int)wg.y;
        const uint4 vv = vf[(gv * NH + h) * 8 + laneC8];
        acc0 = __hfma2(w2, u2h2(vv.x), acc0);
        acc1 = __hfma2(w2, u2h2(vv.y), acc1);
        acc2 = __hfma2(w2, u2h2(vv.z), acc2);
        acc3 = __hfma2(w2, u2h2(vv.w), acc3);
    }

    acc0 = swz_hadd2<0x201F>(acc0); acc1 = swz_hadd2<0x201F>(acc1);
    acc2 = swz_hadd2<0x201F>(acc2); acc3 = swz_hadd2<0x201F>(acc3);
    acc0 = swz_hadd2<0x401F>(acc0); acc1 = swz_hadd2<0x401F>(acc1);
    acc2 = swz_hadd2<0x401F>(acc2); acc3 = swz_hadd2<0x401F>(acc3);
    acc0 = sh32_hadd2(acc0); acc1 = sh32_hadd2(acc1);
    acc2 = sh32_hadd2(acc2); acc3 = sh32_hadd2(acc3);

    if (laneQ8 == 0) {
        const float inv = __builtin_amdgcn_rcpf(S2);
        const float2 a0 = __half22float2(acc0);
        const float2 a1f = __half22float2(acc1);
        const float2 a2f = __half22float2(acc2);
        const float2 a3f = __half22float2(acc3);
        float4* op = (float4*)(out + gid * HD + laneC8 * 8);
        op[0] = make_float4(a0.x * inv, a0.y * inv, a1f.x * inv, a1f.y * inv);
        op[1] = make_float4(a2f.x * inv, a2f.y * inv, a3f.x * inv, a3f.y * inv);
    }
}

extern "C" void kernel_launch(void* const* d_in, const int* in_sizes, int n_in,
                              void* d_out, int out_size, void* d_ws, size_t ws_size,
                              hipStream_t stream) {
    const float* q   = (const float*)d_in[0];
    const float* k   = (const float*)d_in[1];
    const float* v   = (const float*)d_in[2];
    const int*   cu  = (const int*)d_in[3];
    const int*   ti  = (const int*)d_in[4];
    const float* ts  = (const float*)d_in[5];
    float*       out = (float*)d_out;
    const int num_docs = in_sizes[3] - 1;

    __half* kH = (__half*)d_ws;
    __half* vH = kH + KV_ELEMS;

    const int n4 = KV_ELEMS / 4;
    hipLaunchKernelGGL(cvt_fp16, dim3(2 * n4 / 256), dim3(256), 0, stream,
                       (const float4*)k, (const float4*)v,
                       (uint2*)kH, (uint2*)vH);

    const int total_waves = T_TOK * NH;          // 65536 -> 16384 blocks
    hipLaunchKernelGGL(dsa_sparse_attn, dim3(total_waves / 4), dim3(256), 0,
                       stream, q, (const __half*)kH, (const __half*)vH,
                       cu, ti, ts, out, num_docs);
}